// Round 4
// baseline (392.481 us; speedup 1.0000x reference)
//
#include <hip/hip_runtime.h>
#include <math.h>

#define SLEN 2048
#define ND 256
#define NH 24
#define HC 64
#define TWO_PI 6.283185307179586f

typedef __attribute__((ext_vector_type(8))) short short8;
typedef __attribute__((ext_vector_type(16))) float f32x16;

// XOR-swizzle for 128B-row LDS tiles: byte ^= ((row&7)<<4)
#define SWZ(b) ((b) ^ (((b) >> 3) & 0x70))

static __device__ __forceinline__ unsigned short f2bf(float f) {
    union { float f; unsigned int u; } v; v.f = f;
    unsigned int u = v.u;
    return (unsigned short)((u + 0x7FFFu + ((u >> 16) & 1u)) >> 16);
}
static __device__ __forceinline__ unsigned int pack2(float a, float b) {
    return (unsigned int)f2bf(a) | ((unsigned int)f2bf(b) << 16);
}
// HW packed f32->bf16 (RNE): lo -> [15:0], hi -> [31:16]
static __device__ __forceinline__ unsigned int cvtpk(float lo, float hi) {
    unsigned int r;
    asm("v_cvt_pk_bf16_f32 %0, %1, %2" : "=v"(r) : "v"(lo), "v"(hi));
    return r;
}
static __device__ __forceinline__ void gload_lds16(const void* g, void* l) {
    __builtin_amdgcn_global_load_lds(
        (const __attribute__((address_space(1))) void*)(g),
        (__attribute__((address_space(3))) void*)(l), 16, 0, 0);
}

// ---------------- zero partial ----------------
__global__ __launch_bounds__(256) void zero_partial_kernel(float4* __restrict__ p) {
    p[(size_t)blockIdx.x * 256 + threadIdx.x] = make_float4(0.f, 0.f, 0.f, 0.f);
}

// ---------------- fp32 -> bf16 convert ----------------
__global__ __launch_bounds__(256) void f32_to_bf16_kernel(
    const float4* __restrict__ in, uint2* __restrict__ out) {
    const size_t id = (size_t)blockIdx.x * 256 + threadIdx.x;
    float4 v = in[id];
    uint2 u; u.x = pack2(v.x, v.y); u.y = pack2(v.z, v.w);
    out[id] = u;
}

// ---------------- K1: k/q projections -> bf16 [h][s][64] ----------------
__global__ __launch_bounds__(256) void kq_kernel(
    const float* __restrict__ nodes, const float* __restrict__ pos,
    const float* __restrict__ aux,
    const float* __restrict__ Wn, const float* __restrict__ bn,
    const float* __restrict__ Wp, const float* __restrict__ bp,
    const float* __restrict__ Wa,
    unsigned short* __restrict__ kbf, unsigned short* __restrict__ qbf)
{
    __shared__ float n_lds[16][256];
    __shared__ float pf_lds[16][6];
    __shared__ float a_lds[16][16];
    const int tid = threadIdx.x;
    const int sb = blockIdx.x & 127;
    const int oh = blockIdx.x >> 7;
    const int s0 = sb * 16;

    #pragma unroll
    for (int p = 0; p < 4; ++p) {
        int u = tid * 4 + p;
        int r = u >> 6, c4 = u & 63;
        float4 v = *(const float4*)(nodes + (size_t)(s0 + r) * ND + c4 * 4);
        *(float4*)(&n_lds[r][c4 * 4]) = v;
    }
    if (tid < 48) {
        int r = tid / 3, c = tid % 3;
        float pv = pos[(s0 + r) * 3 + c] * TWO_PI;
        pf_lds[r][c] = cosf(pv);
        pf_lds[r][c + 3] = sinf(pv);
    }
    if (tid < 256) {
        int r = tid >> 4, c = tid & 15;
        a_lds[r][c] = aux[(s0 + r) * 16 + c];
    }
    __syncthreads();

    for (int rr = 0; rr < 2; ++rr) {
        const int o = oh * 512 + rr * 256 + tid;
        float accn[16];
        const float bnv = bn[o];
        #pragma unroll
        for (int ss = 0; ss < 16; ++ss) accn[ss] = bnv;
        const float4* wrow = (const float4*)(Wn + (size_t)o * ND);
        for (int d4 = 0; d4 < 64; ++d4) {
            float4 w = wrow[d4];
            #pragma unroll
            for (int ss = 0; ss < 16; ++ss) {
                const float* n = &n_lds[ss][d4 * 4];
                accn[ss] += n[0] * w.x + n[1] * w.y + n[2] * w.z + n[3] * w.w;
            }
        }
        float accp[16];
        const float bpv = bp[o];
        float wpv[6];
        #pragma unroll
        for (int d = 0; d < 6; ++d) wpv[d] = Wp[(size_t)o * 6 + d];
        #pragma unroll
        for (int ss = 0; ss < 16; ++ss) {
            float a = bpv;
            #pragma unroll
            for (int d = 0; d < 6; ++d) a += pf_lds[ss][d] * wpv[d];
            accp[ss] = a;
        }
        float acca[16];
        float wav[16];
        #pragma unroll
        for (int d = 0; d < 16; ++d) wav[d] = Wa[(size_t)o * 16 + d];
        #pragma unroll
        for (int ss = 0; ss < 16; ++ss) {
            float a = 0.f;
            #pragma unroll
            for (int d = 0; d < 16; ++d) a += a_lds[ss][d] * wav[d];
            acca[ss] = a;
        }
        const int h8 = o >> 7;
        const int rem = o & 127;
        const int isq = rem >> 6;
        const int c = rem & 63;
        unsigned short* dst = isq ? qbf : kbf;
        #pragma unroll
        for (int ss = 0; ss < 16; ++ss) {
            const size_t s = s0 + ss;
            dst[((size_t)h8 * SLEN + s) * HC + c]        = f2bf(accn[ss]);
            dst[((size_t)(8 + h8) * SLEN + s) * HC + c]  = f2bf(accp[ss]);
            dst[((size_t)(16 + h8) * SLEN + s) * HC + c] = f2bf(acca[ss]);
        }
    }
}

// ---------------- K2: val GEMM via MFMA -> vt[6144][2048] bf16 ----------------
__global__ __launch_bounds__(256) void val_mfma_kernel(
    const unsigned short* __restrict__ wv_bf, const unsigned short* __restrict__ nodes_bf,
    const float* __restrict__ bv, unsigned short* __restrict__ vt)
{
    __shared__ __align__(16) char lds[131072];  // A: [128 rows][512B], B at +65536
    const int tid = threadIdx.x;
    const int w = tid >> 6, lane = tid & 63;
    const int l31 = lane & 31, lh = lane >> 5;
    const int wg = ((blockIdx.x & 7) * 96) + (blockIdx.x >> 3);  // XCD chunk, bijective
    const int o0 = (wg >> 4) * 128;
    const int s0 = (wg & 15) * 128;

    {
        const int rbase = w * 32;
        const int roff = lane >> 5;
        const int slot = l31 * 16;
        #pragma unroll
        for (int i = 0; i < 16; ++i) {
            const int row = rbase + i * 2 + roff;
            const int colb = slot ^ ((row & 31) << 4);
            gload_lds16(wv_bf + (((size_t)(o0 + row)) << 8) + (colb >> 1),
                        lds + (rbase + i * 2) * 512);
        }
        #pragma unroll
        for (int i = 0; i < 16; ++i) {
            const int row = rbase + i * 2 + roff;
            const int colb = slot ^ ((row & 31) << 4);
            gload_lds16(nodes_bf + (((size_t)(s0 + row)) << 8) + (colb >> 1),
                        lds + 65536 + (rbase + i * 2) * 512);
        }
    }
    __syncthreads();

    const int wm = w >> 1, wn = w & 1;
    f32x16 acc[2][2];
    #pragma unroll
    for (int mf = 0; mf < 2; ++mf)
        #pragma unroll
        for (int nf = 0; nf < 2; ++nf)
            #pragma unroll
            for (int r = 0; r < 16; ++r) acc[mf][nf][r] = 0.f;

    const char* Abase = lds;
    const char* Bbase = lds + 65536;
    #pragma unroll
    for (int kk = 0; kk < 16; ++kk) {
        short8 af[2], bq[2];
        #pragma unroll
        for (int mf = 0; mf < 2; ++mf) {
            const int row = wm * 64 + mf * 32 + l31;
            af[mf] = *(const short8*)(Abase + row * 512 +
                     ((kk * 32 + lh * 16) ^ ((row & 31) << 4)));
        }
        #pragma unroll
        for (int nf = 0; nf < 2; ++nf) {
            const int row = wn * 64 + nf * 32 + l31;
            bq[nf] = *(const short8*)(Bbase + row * 512 +
                     ((kk * 32 + lh * 16) ^ ((row & 31) << 4)));
        }
        #pragma unroll
        for (int mf = 0; mf < 2; ++mf)
            #pragma unroll
            for (int nf = 0; nf < 2; ++nf)
                acc[mf][nf] = __builtin_amdgcn_mfma_f32_32x32x16_bf16(
                    af[mf], bq[nf], acc[mf][nf], 0, 0, 0);
    }

    #pragma unroll
    for (int mf = 0; mf < 2; ++mf) {
        #pragma unroll
        for (int r = 0; r < 16; ++r) {
            const int o = o0 + wm * 64 + mf * 32 + (r & 3) + 8 * (r >> 2) + 4 * lh;
            const float b = bv[o];
            #pragma unroll
            for (int nf = 0; nf < 2; ++nf) {
                const int s = s0 + wn * 64 + nf * 32 + l31;
                vt[(size_t)o * SLEN + s] = f2bf(acc[mf][nf][r] + b);
            }
        }
    }
}

// ---------------- K3: flash attention, barrier-free ----------------
// grid 768 = 24 heads x 32 i-tiles of 64 rows; 2 waves x 32 rows.
// All K/Q/V fragments loaded directly from L2-resident bf16 buffers.
// Only per-wave LDS: P reshuffle tile. NO __syncthreads in the loop.
__global__ __launch_bounds__(128, 2) void attn_kernel(
    const unsigned short* __restrict__ kbf, const unsigned short* __restrict__ qbf,
    const unsigned short* __restrict__ vt, float* __restrict__ partial)
{
    __shared__ __align__(16) char p_raw[2][32 * 128];   // per-wave [i][j] bf16, swizzled
    __shared__ float sc_sm[2][32];

    const int tid = threadIdx.x;
    const int w = tid >> 6, lane = tid & 63;
    const int l31 = lane & 31, lh = lane >> 5;
    const int wg = (blockIdx.x & 7) * 96 + (blockIdx.x >> 3);  // XCD-chunked, bijective
    const int h = wg >> 5, it = wg & 31;
    const int i0 = it * 64;

    const unsigned short* kh = kbf + (size_t)h * SLEN * HC;
    const unsigned short* qh = qbf + (size_t)h * SLEN * HC;
    const unsigned short* vh = vt + (size_t)h * ND * SLEN;

    // persistent k fragments: this wave's 32 rows (i = i0 + w*32 + l31)
    short8 kf[4];
    {
        const unsigned short* kp = kh + (size_t)(i0 + w * 32 + l31) * HC + lh * 8;
        #pragma unroll
        for (int ks = 0; ks < 4; ++ks)
            kf[ks] = *(const short8*)(kp + ks * 16);
    }

    f32x16 acc[8];
    #pragma unroll
    for (int nf = 0; nf < 8; ++nf)
        #pragma unroll
        for (int r = 0; r < 16; ++r) acc[nf][r] = 0.f;
    float m_run = -1e30f, l_run = 0.f;

    for (int jt = 0; jt < SLEN / 64; ++jt) {
        const int j0 = jt * 64;

        // QK^T: S^T[j, i] for j in two 32-blocks; q fragments direct from L2
        f32x16 s0, s1;
        #pragma unroll
        for (int r = 0; r < 16; ++r) { s0[r] = 0.f; s1[r] = 0.f; }
        const unsigned short* q0 = qh + (size_t)(j0 + l31) * HC + lh * 8;
        const unsigned short* q1 = q0 + 32 * HC;
        #pragma unroll
        for (int ks = 0; ks < 4; ++ks) {
            short8 a0 = *(const short8*)(q0 + ks * 16);
            short8 a1 = *(const short8*)(q1 + ks * 16);
            s0 = __builtin_amdgcn_mfma_f32_32x32x16_bf16(a0, kf[ks], s0, 0, 0, 0);
            s1 = __builtin_amdgcn_mfma_f32_32x32x16_bf16(a1, kf[ks], s1, 0, 0, 0);
        }

        // online softmax (i = l31 fixed per lane; 32 j's per lane)
        float tmax = s0[0];
        #pragma unroll
        for (int r = 1; r < 16; ++r) tmax = fmaxf(tmax, s0[r]);
        #pragma unroll
        for (int r = 0; r < 16; ++r) tmax = fmaxf(tmax, s1[r]);
        tmax = fmaxf(tmax, __shfl_xor(tmax, 32));

        if (!__all(tmax - m_run <= 8.0f)) {   // defer-max (T13)
            const float mnew = fmaxf(m_run, tmax);
            const float sc = __expf(m_run - mnew);
            l_run *= sc; m_run = mnew;
            if (lane < 32) sc_sm[w][l31] = sc;
            asm volatile("s_waitcnt lgkmcnt(0)" ::: "memory");
            float scv[16];
            #pragma unroll
            for (int r = 0; r < 16; ++r)
                scv[r] = sc_sm[w][(r & 3) + 8 * (r >> 2) + 4 * lh];
            #pragma unroll
            for (int nf = 0; nf < 8; ++nf)
                #pragma unroll
                for (int r = 0; r < 16; ++r) acc[nf][r] *= scv[r];
        }

        // P = exp(S - m) -> bf16 per-wave LDS tile (cvt_pk), accumulate row-sum
        float psum = 0.f;
        #pragma unroll
        for (int mf = 0; mf < 2; ++mf) {
            #pragma unroll
            for (int qg = 0; qg < 4; ++qg) {
                float e0, e1, e2, e3;
                if (mf == 0) {
                    e0 = __expf(s0[qg * 4 + 0] - m_run); e1 = __expf(s0[qg * 4 + 1] - m_run);
                    e2 = __expf(s0[qg * 4 + 2] - m_run); e3 = __expf(s0[qg * 4 + 3] - m_run);
                } else {
                    e0 = __expf(s1[qg * 4 + 0] - m_run); e1 = __expf(s1[qg * 4 + 1] - m_run);
                    e2 = __expf(s1[qg * 4 + 2] - m_run); e3 = __expf(s1[qg * 4 + 3] - m_run);
                }
                psum += (e0 + e1) + (e2 + e3);
                uint2 u; u.x = cvtpk(e0, e1); u.y = cvtpk(e2, e3);
                const int jb = mf * 32 + qg * 8 + lh * 4;
                *(uint2*)(p_raw[w] + SWZ(l31 * 128 + jb * 2)) = u;
            }
        }
        psum += __shfl_xor(psum, 32);
        l_run += psum;

        // PV: acc[i, d] += P[i, j] * v^T[d, j]; V fragments direct from L2
        #pragma unroll
        for (int ks = 0; ks < 4; ++ks) {
            short8 pa = *(const short8*)(p_raw[w] + SWZ(l31 * 128 + (ks * 16 + lh * 8) * 2));
            const unsigned short* vp = vh + (size_t)l31 * SLEN + j0 + ks * 16 + lh * 8;
            #pragma unroll
            for (int nf = 0; nf < 8; ++nf) {
                short8 vb = *(const short8*)(vp + (size_t)nf * 32 * SLEN);
                acc[nf] = __builtin_amdgcn_mfma_f32_32x32x16_bf16(pa, vb, acc[nf], 0, 0, 0);
            }
        }
    }

    // epilogue: divide by l, add into per-head-group partial
    if (lane < 32) sc_sm[w][l31] = 1.0f / l_run;
    asm volatile("s_waitcnt lgkmcnt(0)" ::: "memory");
    float lv[16];
    #pragma unroll
    for (int r = 0; r < 16; ++r)
        lv[r] = sc_sm[w][(r & 3) + 8 * (r >> 2) + 4 * lh];
    float* pb = partial + (size_t)(h / 3) * (SLEN * ND);
    #pragma unroll
    for (int nf = 0; nf < 8; ++nf) {
        const int d = nf * 32 + l31;
        #pragma unroll
        for (int r = 0; r < 16; ++r) {
            const int i = i0 + w * 32 + (r & 3) + 8 * (r >> 2) + 4 * lh;
            atomicAdd(pb + (size_t)i * ND + d, acc[nf][r] * lv[r]);
        }
    }
}

// ---------------- K4: reduce 8 partials -> out ----------------
__global__ __launch_bounds__(256) void reduce_kernel(
    const float4* __restrict__ partial, float4* __restrict__ out)
{
    const size_t id = (size_t)blockIdx.x * 256 + threadIdx.x;
    float4 s = make_float4(0.f, 0.f, 0.f, 0.f);
    #pragma unroll
    for (int g = 0; g < 8; ++g) {
        float4 v = partial[g * (SLEN * ND / 4) + id];
        s.x += v.x; s.y += v.y; s.z += v.z; s.w += v.w;
    }
    out[id] = s;
}

extern "C" void kernel_launch(void* const* d_in, const int* in_sizes, int n_in,
                              void* d_out, int out_size, void* d_ws, size_t ws_size,
                              hipStream_t stream) {
    const float* nodes = (const float*)d_in[0];
    const float* pos   = (const float*)d_in[1];
    const float* aux   = (const float*)d_in[2];
    const float* Wn    = (const float*)d_in[3];
    const float* bn    = (const float*)d_in[4];
    const float* Wp    = (const float*)d_in[5];
    const float* bp    = (const float*)d_in[6];
    const float* Wa    = (const float*)d_in[7];
    const float* Wv    = (const float*)d_in[8];
    const float* bv    = (const float*)d_in[9];
    float* out = (float*)d_out;

    const size_t KQ = (size_t)SLEN * NH * HC;          // 3,145,728 bf16 each
    const size_t VT = (size_t)NH * ND * SLEN;          // 12,582,912 bf16
    const size_t PART = (size_t)8 * SLEN * ND;         // 4,194,304 floats
    const size_t WVBF = (size_t)6144 * ND;             // bf16
    const size_t NDBF = (size_t)SLEN * ND;             // bf16
    const size_t need = (2 * KQ + VT + WVBF + NDBF) * 2 + PART * 4;

    if (ws_size < need) return;

    unsigned short* kbf = (unsigned short*)d_ws;
    unsigned short* qbf = kbf + KQ;
    unsigned short* vt  = qbf + KQ;
    unsigned short* wv_bf = vt + VT;
    unsigned short* nodes_bf = wv_bf + WVBF;
    float* partial = (float*)(nodes_bf + NDBF);

    zero_partial_kernel<<<PART / 1024, 256, 0, stream>>>((float4*)partial);
    f32_to_bf16_kernel<<<1536, 256, 0, stream>>>((const float4*)Wv, (uint2*)wv_bf);
    f32_to_bf16_kernel<<<512, 256, 0, stream>>>((const float4*)nodes, (uint2*)nodes_bf);
    kq_kernel<<<256, 256, 0, stream>>>(nodes, pos, aux, Wn, bn, Wp, bp, Wa, kbf, qbf);
    val_mfma_kernel<<<768, 256, 0, stream>>>(wv_bf, nodes_bf, bv, vt);
    attn_kernel<<<768, 128, 0, stream>>>(kbf, qbf, vt, partial);
    reduce_kernel<<<512, 256, 0, stream>>>((const float4*)partial, (float4*)out);
}

// Round 5
// 224.988 us; speedup vs baseline: 1.7445x; 1.7445x over previous
//
#include <hip/hip_runtime.h>
#include <math.h>

#define SLEN 2048
#define ND 256
#define NH 24
#define HC 64
#define TWO_PI 6.283185307179586f
#define NT 32   // j-tiles of 64

typedef __attribute__((ext_vector_type(8))) short short8;
typedef __attribute__((ext_vector_type(16))) float f32x16;
typedef __attribute__((ext_vector_type(2))) unsigned int uint2e;

static __device__ __forceinline__ unsigned short f2bf(float f) {
    union { float f; unsigned int u; } v; v.f = f;
    unsigned int u = v.u;
    return (unsigned short)((u + 0x7FFFu + ((u >> 16) & 1u)) >> 16);
}
static __device__ __forceinline__ unsigned int pack2(float a, float b) {
    return (unsigned int)f2bf(a) | ((unsigned int)f2bf(b) << 16);
}
// HW packed f32->bf16 (RNE): lo -> [15:0], hi -> [31:16]
static __device__ __forceinline__ unsigned int cvtpk(float lo, float hi) {
    unsigned int r;
    asm("v_cvt_pk_bf16_f32 %0, %1, %2" : "=v"(r) : "v"(lo), "v"(hi));
    return r;
}
static __device__ __forceinline__ void gload_lds16(const void* g, void* l) {
    __builtin_amdgcn_global_load_lds(
        (const __attribute__((address_space(1))) void*)(g),
        (__attribute__((address_space(3))) void*)(l), 16, 0, 0);
}

// ---------------- zero partial ----------------
__global__ __launch_bounds__(256) void zero_partial_kernel(float4* __restrict__ p) {
    p[(size_t)blockIdx.x * 256 + threadIdx.x] = make_float4(0.f, 0.f, 0.f, 0.f);
}

// ---------------- fp32 -> bf16 convert ----------------
__global__ __launch_bounds__(256) void f32_to_bf16_kernel(
    const float4* __restrict__ in, uint2* __restrict__ out) {
    const size_t id = (size_t)blockIdx.x * 256 + threadIdx.x;
    float4 v = in[id];
    uint2 u; u.x = pack2(v.x, v.y); u.y = pack2(v.z, v.w);
    out[id] = u;
}

// ---------------- pos featurization: pos_f[s][8] = cos x3, sin x3, pad ----------------
__global__ __launch_bounds__(256) void posf_kernel(
    const float* __restrict__ pos, float* __restrict__ pos_f) {
    const int s = blockIdx.x * 256 + threadIdx.x;
    if (s < SLEN) {
        #pragma unroll
        for (int c = 0; c < 3; ++c) {
            float v = pos[s * 3 + c] * TWO_PI;
            pos_f[s * 8 + c] = cosf(v);
            pos_f[s * 8 + 3 + c] = sinf(v);
        }
        pos_f[s * 8 + 6] = 0.f; pos_f[s * 8 + 7] = 0.f;
    }
}

// ---------------- unified MFMA GEMM ----------------
// bid < 768: val: C[o][s] = Wv[o]·nodes[s] + bv -> vt bf16 [6144][2048]
// bid >= 768: kq:  C[s][o] = nodes[s]·Wn[o]     -> kqtmp f32 [2048][1024]
// 128x128 tile, K=256 in LDS, 4 waves 2x2, mfma_32x32x16_bf16.
__global__ __launch_bounds__(256) void gemm_kernel(
    const unsigned short* __restrict__ wv_bf, const unsigned short* __restrict__ wn_bf,
    const unsigned short* __restrict__ nodes_bf, const float* __restrict__ bv,
    unsigned short* __restrict__ vt, float* __restrict__ kqtmp)
{
    __shared__ __align__(16) char lds[131072];  // A: [128][512B], B at +65536
    const int tid = threadIdx.x;
    const int w = tid >> 6, lane = tid & 63;
    const int l31 = lane & 31, lh = lane >> 5;
    const int bid = blockIdx.x;
    const bool isval = bid < 768;
    int o0, s0;
    const unsigned short *Aptr, *Bptr;
    if (isval) {
        const int wg = ((bid & 7) * 96) + (bid >> 3);  // XCD chunk, bijective
        o0 = (wg >> 4) * 128; s0 = (wg & 15) * 128;
        Aptr = wv_bf + (size_t)o0 * 256; Bptr = nodes_bf + (size_t)s0 * 256;
    } else {
        const int b = bid - 768;
        o0 = (b >> 4) * 128; s0 = (b & 15) * 128;
        Aptr = nodes_bf + (size_t)s0 * 256; Bptr = wn_bf + (size_t)o0 * 256;
    }

    {
        const int rbase = w * 32;
        const int roff = lane >> 5;
        const int slot = l31 * 16;
        #pragma unroll
        for (int i = 0; i < 16; ++i) {
            const int row = rbase + i * 2 + roff;
            const int colb = slot ^ ((row & 31) << 4);
            gload_lds16(Aptr + (((size_t)row) << 8) + (colb >> 1),
                        lds + (rbase + i * 2) * 512);
        }
        #pragma unroll
        for (int i = 0; i < 16; ++i) {
            const int row = rbase + i * 2 + roff;
            const int colb = slot ^ ((row & 31) << 4);
            gload_lds16(Bptr + (((size_t)row) << 8) + (colb >> 1),
                        lds + 65536 + (rbase + i * 2) * 512);
        }
    }
    __syncthreads();

    const int wm = w >> 1, wn = w & 1;
    f32x16 acc[2][2];
    #pragma unroll
    for (int mf = 0; mf < 2; ++mf)
        #pragma unroll
        for (int nf = 0; nf < 2; ++nf)
            #pragma unroll
            for (int r = 0; r < 16; ++r) acc[mf][nf][r] = 0.f;

    const char* Abase = lds;
    const char* Bbase = lds + 65536;
    #pragma unroll
    for (int kk = 0; kk < 16; ++kk) {
        short8 af[2], bq[2];
        #pragma unroll
        for (int mf = 0; mf < 2; ++mf) {
            const int row = wm * 64 + mf * 32 + l31;
            af[mf] = *(const short8*)(Abase + row * 512 +
                     ((kk * 32 + lh * 16) ^ ((row & 31) << 4)));
        }
        #pragma unroll
        for (int nf = 0; nf < 2; ++nf) {
            const int row = wn * 64 + nf * 32 + l31;
            bq[nf] = *(const short8*)(Bbase + row * 512 +
                     ((kk * 32 + lh * 16) ^ ((row & 31) << 4)));
        }
        #pragma unroll
        for (int mf = 0; mf < 2; ++mf)
            #pragma unroll
            for (int nf = 0; nf < 2; ++nf)
                acc[mf][nf] = __builtin_amdgcn_mfma_f32_32x32x16_bf16(
                    af[mf], bq[nf], acc[mf][nf], 0, 0, 0);
    }

    if (isval) {
        #pragma unroll
        for (int mf = 0; mf < 2; ++mf) {
            #pragma unroll
            for (int r = 0; r < 16; ++r) {
                const int o = o0 + wm * 64 + mf * 32 + (r & 3) + 8 * (r >> 2) + 4 * lh;
                const float b = bv[o];
                #pragma unroll
                for (int nf = 0; nf < 2; ++nf) {
                    const int s = s0 + wn * 64 + nf * 32 + l31;
                    vt[(size_t)o * SLEN + s] = f2bf(acc[mf][nf][r] + b);
                }
            }
        }
    } else {
        #pragma unroll
        for (int mf = 0; mf < 2; ++mf) {
            #pragma unroll
            for (int r = 0; r < 16; ++r) {
                const int srow = s0 + wm * 64 + mf * 32 + (r & 3) + 8 * (r >> 2) + 4 * lh;
                #pragma unroll
                for (int nf = 0; nf < 2; ++nf) {
                    const int o = o0 + wn * 64 + nf * 32 + l31;
                    kqtmp[(size_t)srow * 1024 + o] = acc[mf][nf][r];
                }
            }
        }
    }
}

// ---------------- kq epilogue: add pos/aux projections + bias, scatter bf16 [h][s][64] ----------------
__global__ __launch_bounds__(256) void kq_epi_kernel(
    const float* __restrict__ kqtmp, const float* __restrict__ pos_f,
    const float* __restrict__ aux, const float* __restrict__ bn,
    const float* __restrict__ bp, const float* __restrict__ Wp,
    const float* __restrict__ Wa,
    unsigned short* __restrict__ kbf, unsigned short* __restrict__ qbf)
{
    const int tid = threadIdx.x;
    const int s = blockIdx.x >> 2;
    const int o = (blockIdx.x & 3) * 256 + tid;

    const float vn = kqtmp[(size_t)s * 1024 + o] + bn[o];
    float vp = bp[o];
    #pragma unroll
    for (int d = 0; d < 6; ++d) vp += pos_f[s * 8 + d] * Wp[o * 6 + d];
    float va = 0.f;
    #pragma unroll
    for (int d = 0; d < 16; ++d) va += aux[s * 16 + d] * Wa[o * 16 + d];

    const int h8 = o >> 7, rem = o & 127, isq = rem >> 6, c = rem & 63;
    unsigned short* dst = isq ? qbf : kbf;
    dst[((size_t)h8 * SLEN + s) * HC + c]        = f2bf(vn);
    dst[((size_t)(8 + h8) * SLEN + s) * HC + c]  = f2bf(vp);
    dst[((size_t)(16 + h8) * SLEN + s) * HC + c] = f2bf(va);
}

// ---------------- K3: flash attention ----------------
// grid 384 = 24 heads x 16 i-tiles of 128. 4 waves: wi = w>>1 (i-half 64), wd = w&1 (d-half 128).
// Swapped QK^T; P in-register via cvt_pk + permlane32_swap; q/V double-buffered in LDS
// via global_load_lds prefetch (T3 2-phase).
__global__ __launch_bounds__(256, 2) void attn_kernel(
    const unsigned short* __restrict__ kbf, const unsigned short* __restrict__ qbf,
    const unsigned short* __restrict__ vt, float* __restrict__ partial)
{
    __shared__ __align__(16) char smem[81920];  // buf b at b*40960: q [64][128B], v [256][128B] at +8192

    const int tid = threadIdx.x;
    const int w = tid >> 6, lane = tid & 63;
    const int l31 = lane & 31, lh = lane >> 5;
    const int wi = w >> 1, wd = w & 1;
    const int wg = (blockIdx.x & 7) * 48 + (blockIdx.x >> 3);  // XCD-chunked, bijective
    const int h = wg >> 4, it = wg & 15;
    const int i0 = it * 128;

    const unsigned short* kh = kbf + (size_t)h * SLEN * HC;
    const unsigned short* qh = qbf + (size_t)h * SLEN * HC;
    const unsigned short* vh = vt + (size_t)h * ND * SLEN;

    // persistent k fragments (B-operand of QK): 2 i-blocks x 4 k-steps
    short8 kf[2][4];
    #pragma unroll
    for (int mm = 0; mm < 2; ++mm) {
        const unsigned short* kp = kh + (size_t)(i0 + wi * 64 + mm * 32 + l31) * HC + lh * 8;
        #pragma unroll
        for (int ks = 0; ks < 4; ++ks) kf[mm][ks] = *(const short8*)(kp + ks * 16);
    }

    f32x16 acc[2][4];
    #pragma unroll
    for (int mm = 0; mm < 2; ++mm)
        #pragma unroll
        for (int nf = 0; nf < 4; ++nf)
            #pragma unroll
            for (int r = 0; r < 16; ++r) acc[mm][nf][r] = 0.f;
    float m_run[2] = {-1e30f, -1e30f}, l_run[2] = {0.f, 0.f};

    // stage tile jt into buffer at byte offset bufo (q: 2 insts/wave, v: 8 insts/wave)
    auto stage = [&](int bufo, int jt) {
        const int j0n = jt * 64;
        #pragma unroll
        for (int i = 0; i < 2; ++i) {
            const int t = w * 2 + i;
            const int row = t * 8 + (lane >> 3);
            const int cb = ((lane & 7) << 4) ^ ((row & 7) << 4);
            gload_lds16(qh + (size_t)(j0n + row) * HC + (cb >> 1),
                        smem + bufo + t * 1024);
        }
        #pragma unroll
        for (int i = 0; i < 8; ++i) {
            const int t = w * 8 + i;
            const int row = t * 8 + (lane >> 3);
            const int cb = ((lane & 7) << 4) ^ ((row & 7) << 4);
            gload_lds16(vh + (size_t)row * SLEN + j0n + (cb >> 1),
                        smem + bufo + 8192 + t * 1024);
        }
    };

    // softmax + pack one 32-j S-block into two A-fragments (P in-register)
    auto softpack = [&](f32x16& S, int mm, uint4& p0, uint4& p1) {
        float tmax = S[0];
        #pragma unroll
        for (int r = 1; r < 16; ++r) tmax = fmaxf(tmax, S[r]);
        tmax = fmaxf(tmax, __shfl_xor(tmax, 32));
        if (!__all(tmax - m_run[mm] <= 8.0f)) {   // defer-max (T13)
            const float mnew = fmaxf(m_run[mm], tmax);
            const float sc = __expf(m_run[mm] - mnew);
            l_run[mm] *= sc; m_run[mm] = mnew;
            #pragma unroll
            for (int r = 0; r < 16; ++r) {
                const float scv = __shfl(sc, (r & 3) + 8 * (r >> 2) + 4 * lh);
                #pragma unroll
                for (int nf = 0; nf < 4; ++nf) acc[mm][nf][r] *= scv;
            }
        }
        float psum = 0.f;
        #pragma unroll
        for (int r = 0; r < 16; ++r) {
            S[r] = __expf(S[r] - m_run[mm]);
            psum += S[r];
        }
        psum += __shfl_xor(psum, 32);
        l_run[mm] += psum;
        // permlane32_swap: swap(X=low-pair, Y=high-pair) -> {word_lo, word_hi}
        uint2e r1 = __builtin_amdgcn_permlane32_swap(cvtpk(S[0], S[1]), cvtpk(S[4], S[5]), false, false);
        uint2e r2 = __builtin_amdgcn_permlane32_swap(cvtpk(S[2], S[3]), cvtpk(S[6], S[7]), false, false);
        uint2e r3 = __builtin_amdgcn_permlane32_swap(cvtpk(S[8], S[9]), cvtpk(S[12], S[13]), false, false);
        uint2e r4 = __builtin_amdgcn_permlane32_swap(cvtpk(S[10], S[11]), cvtpk(S[14], S[15]), false, false);
        p0 = make_uint4(r1[0], r2[0], r1[1], r2[1]);
        p1 = make_uint4(r3[0], r4[0], r3[1], r4[1]);
    };

    stage(0, 0);
    __syncthreads();

    for (int jt = 0; jt < NT; ++jt) {
        const int bo = (jt & 1) * 40960;
        if (jt + 1 < NT) stage(40960 - bo, jt + 1);
        const char* qb = smem + bo;
        const char* vb = smem + bo + 8192;

        #pragma unroll
        for (int jh = 0; jh < 2; ++jh) {
            // QK^T: A = q (from LDS), B = kf
            f32x16 s0, s1;
            #pragma unroll
            for (int r = 0; r < 16; ++r) { s0[r] = 0.f; s1[r] = 0.f; }
            const int qrow = jh * 32 + l31;
            const int qsw = (qrow & 7) << 4;
            __builtin_amdgcn_s_setprio(1);
            #pragma unroll
            for (int ks = 0; ks < 4; ++ks) {
                short8 a = *(const short8*)(qb + qrow * 128 + ((ks * 32 + lh * 16) ^ qsw));
                s0 = __builtin_amdgcn_mfma_f32_32x32x16_bf16(a, kf[0][ks], s0, 0, 0, 0);
                s1 = __builtin_amdgcn_mfma_f32_32x32x16_bf16(a, kf[1][ks], s1, 0, 0, 0);
            }
            __builtin_amdgcn_s_setprio(0);

            uint4 pf[2][2];
            softpack(s0, 0, pf[0][0], pf[0][1]);
            softpack(s1, 1, pf[1][0], pf[1][1]);

            // PV: A = P (regs), B = V^T (LDS [d][j])
            __builtin_amdgcn_s_setprio(1);
            #pragma unroll
            for (int ksl = 0; ksl < 2; ++ksl) {
                const short8 pa0 = *(const short8*)&pf[0][ksl];
                const short8 pa1 = *(const short8*)&pf[1][ksl];
                #pragma unroll
                for (int nf = 0; nf < 4; ++nf) {
                    const int row = wd * 128 + nf * 32 + l31;
                    const int colb = ((jh * 32 + ksl * 16 + lh * 8) * 2) ^ ((row & 7) << 4);
                    short8 vfrag = *(const short8*)(vb + row * 128 + colb);
                    acc[0][nf] = __builtin_amdgcn_mfma_f32_32x32x16_bf16(pa0, vfrag, acc[0][nf], 0, 0, 0);
                    acc[1][nf] = __builtin_amdgcn_mfma_f32_32x32x16_bf16(pa1, vfrag, acc[1][nf], 0, 0, 0);
                }
            }
            __builtin_amdgcn_s_setprio(0);
        }
        __syncthreads();
    }

    // epilogue: divide by l (broadcast via shfl), atomic head-group sum
    float* pb = partial + (size_t)(h / 3) * (SLEN * ND);
    #pragma unroll
    for (int mm = 0; mm < 2; ++mm) {
        const float invm = 1.0f / l_run[mm];
        float lv[16];
        #pragma unroll
        for (int r = 0; r < 16; ++r)
            lv[r] = __shfl(invm, (r & 3) + 8 * (r >> 2) + 4 * lh);
        #pragma unroll
        for (int nf = 0; nf < 4; ++nf) {
            const int d = wd * 128 + nf * 32 + l31;
            #pragma unroll
            for (int r = 0; r < 16; ++r) {
                const int i = i0 + wi * 64 + mm * 32 + (r & 3) + 8 * (r >> 2) + 4 * lh;
                atomicAdd(pb + (size_t)i * ND + d, acc[mm][nf][r] * lv[r]);
            }
        }
    }
}

// ---------------- K4: reduce 8 partials -> out ----------------
__global__ __launch_bounds__(256) void reduce_kernel(
    const float4* __restrict__ partial, float4* __restrict__ out)
{
    const size_t id = (size_t)blockIdx.x * 256 + threadIdx.x;
    float4 s = make_float4(0.f, 0.f, 0.f, 0.f);
    #pragma unroll
    for (int g = 0; g < 8; ++g) {
        float4 v = partial[g * (SLEN * ND / 4) + id];
        s.x += v.x; s.y += v.y; s.z += v.z; s.w += v.w;
    }
    out[id] = s;
}

extern "C" void kernel_launch(void* const* d_in, const int* in_sizes, int n_in,
                              void* d_out, int out_size, void* d_ws, size_t ws_size,
                              hipStream_t stream) {
    const float* nodes = (const float*)d_in[0];
    const float* pos   = (const float*)d_in[1];
    const float* aux   = (const float*)d_in[2];
    const float* Wn    = (const float*)d_in[3];
    const float* bn    = (const float*)d_in[4];
    const float* Wp    = (const float*)d_in[5];
    const float* bp    = (const float*)d_in[6];
    const float* Wa    = (const float*)d_in[7];
    const float* Wv    = (const float*)d_in[8];
    const float* bv    = (const float*)d_in[9];
    float* out = (float*)d_out;

    const size_t KQ   = (size_t)SLEN * NH * HC;   // 3,145,728 bf16 each
    const size_t VT   = (size_t)NH * ND * SLEN;   // 12,582,912 bf16
    const size_t WVBF = (size_t)6144 * ND;        // 1,572,864 bf16
    const size_t WNBF = (size_t)1024 * ND;        // 262,144 bf16
    const size_t NDBF = (size_t)SLEN * ND;        // 524,288 bf16
    const size_t POSF = (size_t)SLEN * 8;         // 16,384 f32
    const size_t KQT  = (size_t)SLEN * 1024;      // 2,097,152 f32
    const size_t PART = (size_t)8 * SLEN * ND;    // 4,194,304 f32
    const size_t need = (2 * KQ + VT + WVBF + WNBF + NDBF) * 2 + (POSF + KQT + PART) * 4;

    if (ws_size < need) return;

    unsigned short* kbf = (unsigned short*)d_ws;
    unsigned short* qbf = kbf + KQ;
    unsigned short* vt  = qbf + KQ;
    unsigned short* wv_bf = vt + VT;
    unsigned short* wn_bf = wv_bf + WVBF;
    unsigned short* nodes_bf = wn_bf + WNBF;
    float* pos_f   = (float*)(nodes_bf + NDBF);
    float* kqtmp   = pos_f + POSF;
    float* partial = kqtmp + KQT;

    zero_partial_kernel<<<PART / 1024, 256, 0, stream>>>((float4*)partial);
    f32_to_bf16_kernel<<<1536, 256, 0, stream>>>((const float4*)Wv, (uint2*)wv_bf);
    f32_to_bf16_kernel<<<256, 256, 0, stream>>>((const float4*)Wn, (uint2*)wn_bf);
    f32_to_bf16_kernel<<<512, 256, 0, stream>>>((const float4*)nodes, (uint2*)nodes_bf);
    posf_kernel<<<8, 256, 0, stream>>>(pos, pos_f);
    gemm_kernel<<<896, 256, 0, stream>>>(wv_bf, wn_bf, nodes_bf, bv, vt, kqtmp);
    kq_epi_kernel<<<8192, 256, 0, stream>>>(kqtmp, pos_f, aux, bn, bp, Wp, Wa, kbf, qbf);
    attn_kernel<<<384, 256, 0, stream>>>(kbf, qbf, vt, partial);
    reduce_kernel<<<512, 256, 0, stream>>>((const float4*)partial, (float4*)out);
}

// Round 6
// 173.461 us; speedup vs baseline: 2.2626x; 1.2971x over previous
//
#include <hip/hip_runtime.h>
#include <math.h>

#define SLEN 2048
#define ND 256
#define NH 24
#define HC 64
#define TWO_PI 6.283185307179586f
#define NT 64   // j-tiles of 32

typedef __attribute__((ext_vector_type(8))) short short8;
typedef __attribute__((ext_vector_type(16))) float f32x16;
typedef __attribute__((ext_vector_type(2))) unsigned int uint2e;

static __device__ __forceinline__ unsigned short f2bf(float f) {
    union { float f; unsigned int u; } v; v.f = f;
    unsigned int u = v.u;
    return (unsigned short)((u + 0x7FFFu + ((u >> 16) & 1u)) >> 16);
}
static __device__ __forceinline__ unsigned int pack2(float a, float b) {
    return (unsigned int)f2bf(a) | ((unsigned int)f2bf(b) << 16);
}
// HW packed f32->bf16 (RNE): lo -> [15:0], hi -> [31:16]
static __device__ __forceinline__ unsigned int cvtpk(float lo, float hi) {
    unsigned int r;
    asm("v_cvt_pk_bf16_f32 %0, %1, %2" : "=v"(r) : "v"(lo), "v"(hi));
    return r;
}
static __device__ __forceinline__ void gload_lds16(const void* g, void* l) {
    __builtin_amdgcn_global_load_lds(
        (const __attribute__((address_space(1))) void*)(g),
        (__attribute__((address_space(3))) void*)(l), 16, 0, 0);
}

// ---------------- zero partial ----------------
__global__ __launch_bounds__(256) void zero_partial_kernel(float4* __restrict__ p) {
    p[(size_t)blockIdx.x * 256 + threadIdx.x] = make_float4(0.f, 0.f, 0.f, 0.f);
}

// ---------------- fp32 -> bf16 convert ----------------
__global__ __launch_bounds__(256) void f32_to_bf16_kernel(
    const float4* __restrict__ in, uint2* __restrict__ out) {
    const size_t id = (size_t)blockIdx.x * 256 + threadIdx.x;
    float4 v = in[id];
    uint2 u; u.x = pack2(v.x, v.y); u.y = pack2(v.z, v.w);
    out[id] = u;
}

// ---------------- pos featurization: pos_f[s][8] = cos x3, sin x3, pad ----------------
__global__ __launch_bounds__(256) void posf_kernel(
    const float* __restrict__ pos, float* __restrict__ pos_f) {
    const int s = blockIdx.x * 256 + threadIdx.x;
    if (s < SLEN) {
        #pragma unroll
        for (int c = 0; c < 3; ++c) {
            float v = pos[s * 3 + c] * TWO_PI;
            pos_f[s * 8 + c] = cosf(v);
            pos_f[s * 8 + 3 + c] = sinf(v);
        }
        pos_f[s * 8 + 6] = 0.f; pos_f[s * 8 + 7] = 0.f;
    }
}

// ---------------- unified MFMA GEMM ----------------
// bid < 768: val: C[o][s] = Wv[o]·nodes[s] + bv -> vt bf16 [6144][2048]
// bid >= 768: kq:  C[s][o] = nodes[s]·Wn[o]     -> kqtmp f32 [2048][1024]
__global__ __launch_bounds__(256) void gemm_kernel(
    const unsigned short* __restrict__ wv_bf, const unsigned short* __restrict__ wn_bf,
    const unsigned short* __restrict__ nodes_bf, const float* __restrict__ bv,
    unsigned short* __restrict__ vt, float* __restrict__ kqtmp)
{
    __shared__ __align__(16) char lds[131072];  // A: [128][512B], B at +65536
    const int tid = threadIdx.x;
    const int w = tid >> 6, lane = tid & 63;
    const int l31 = lane & 31, lh = lane >> 5;
    const int bid = blockIdx.x;
    const bool isval = bid < 768;
    int o0, s0;
    const unsigned short *Aptr, *Bptr;
    if (isval) {
        const int wg = ((bid & 7) * 96) + (bid >> 3);  // XCD chunk, bijective
        o0 = (wg >> 4) * 128; s0 = (wg & 15) * 128;
        Aptr = wv_bf + (size_t)o0 * 256; Bptr = nodes_bf + (size_t)s0 * 256;
    } else {
        const int b = bid - 768;
        o0 = (b >> 4) * 128; s0 = (b & 15) * 128;
        Aptr = nodes_bf + (size_t)s0 * 256; Bptr = wn_bf + (size_t)o0 * 256;
    }

    {
        const int rbase = w * 32;
        const int roff = lane >> 5;
        const int slot = l31 * 16;
        #pragma unroll
        for (int i = 0; i < 16; ++i) {
            const int row = rbase + i * 2 + roff;
            const int colb = slot ^ ((row & 31) << 4);
            gload_lds16(Aptr + (((size_t)row) << 8) + (colb >> 1),
                        lds + (rbase + i * 2) * 512);
        }
        #pragma unroll
        for (int i = 0; i < 16; ++i) {
            const int row = rbase + i * 2 + roff;
            const int colb = slot ^ ((row & 31) << 4);
            gload_lds16(Bptr + (((size_t)row) << 8) + (colb >> 1),
                        lds + 65536 + (rbase + i * 2) * 512);
        }
    }
    __syncthreads();

    const int wm = w >> 1, wn = w & 1;
    f32x16 acc[2][2];
    #pragma unroll
    for (int mf = 0; mf < 2; ++mf)
        #pragma unroll
        for (int nf = 0; nf < 2; ++nf)
            #pragma unroll
            for (int r = 0; r < 16; ++r) acc[mf][nf][r] = 0.f;

    const char* Abase = lds;
    const char* Bbase = lds + 65536;
    #pragma unroll
    for (int kk = 0; kk < 16; ++kk) {
        short8 af[2], bq[2];
        #pragma unroll
        for (int mf = 0; mf < 2; ++mf) {
            const int row = wm * 64 + mf * 32 + l31;
            af[mf] = *(const short8*)(Abase + row * 512 +
                     ((kk * 32 + lh * 16) ^ ((row & 31) << 4)));
        }
        #pragma unroll
        for (int nf = 0; nf < 2; ++nf) {
            const int row = wn * 64 + nf * 32 + l31;
            bq[nf] = *(const short8*)(Bbase + row * 512 +
                     ((kk * 32 + lh * 16) ^ ((row & 31) << 4)));
        }
        #pragma unroll
        for (int mf = 0; mf < 2; ++mf)
            #pragma unroll
            for (int nf = 0; nf < 2; ++nf)
                acc[mf][nf] = __builtin_amdgcn_mfma_f32_32x32x16_bf16(
                    af[mf], bq[nf], acc[mf][nf], 0, 0, 0);
    }

    if (isval) {
        #pragma unroll
        for (int mf = 0; mf < 2; ++mf) {
            #pragma unroll
            for (int r = 0; r < 16; ++r) {
                const int o = o0 + wm * 64 + mf * 32 + (r & 3) + 8 * (r >> 2) + 4 * lh;
                const float b = bv[o];
                #pragma unroll
                for (int nf = 0; nf < 2; ++nf) {
                    const int s = s0 + wn * 64 + nf * 32 + l31;
                    vt[(size_t)o * SLEN + s] = f2bf(acc[mf][nf][r] + b);
                }
            }
        }
    } else {
        #pragma unroll
        for (int mf = 0; mf < 2; ++mf) {
            #pragma unroll
            for (int r = 0; r < 16; ++r) {
                const int srow = s0 + wm * 64 + mf * 32 + (r & 3) + 8 * (r >> 2) + 4 * lh;
                #pragma unroll
                for (int nf = 0; nf < 2; ++nf) {
                    const int o = o0 + wn * 64 + nf * 32 + l31;
                    kqtmp[(size_t)srow * 1024 + o] = acc[mf][nf][r];
                }
            }
        }
    }
}

// ---------------- kq epilogue: add pos/aux projections + bias, scatter bf16 [h][s][64] ----------------
__global__ __launch_bounds__(256) void kq_epi_kernel(
    const float* __restrict__ kqtmp, const float* __restrict__ pos_f,
    const float* __restrict__ aux, const float* __restrict__ bn,
    const float* __restrict__ bp, const float* __restrict__ Wp,
    const float* __restrict__ Wa,
    unsigned short* __restrict__ kbf, unsigned short* __restrict__ qbf)
{
    const int tid = threadIdx.x;
    const int s = blockIdx.x >> 2;
    const int o = (blockIdx.x & 3) * 256 + tid;

    const float vn = kqtmp[(size_t)s * 1024 + o] + bn[o];
    float vp = bp[o];
    #pragma unroll
    for (int d = 0; d < 6; ++d) vp += pos_f[s * 8 + d] * Wp[o * 6 + d];
    float va = 0.f;
    #pragma unroll
    for (int d = 0; d < 16; ++d) va += aux[s * 16 + d] * Wa[o * 16 + d];

    const int h8 = o >> 7, rem = o & 127, isq = rem >> 6, c = rem & 63;
    unsigned short* dst = isq ? qbf : kbf;
    dst[((size_t)h8 * SLEN + s) * HC + c]        = f2bf(vn);
    dst[((size_t)(8 + h8) * SLEN + s) * HC + c]  = f2bf(vp);
    dst[((size_t)(16 + h8) * SLEN + s) * HC + c] = f2bf(va);
}

// ---------------- K3: flash attention ----------------
// grid 768 = 24 heads x 32 i-tiles of 64 rows -> exactly 3 blocks/CU.
// 4 waves: wi = w>>1 (i-block of 32), wd = w&1 (d-half of 128).
// j-tile 32, double-buffered LDS 2 x (q 4KB + V 16KB) = 40KB -> 3 blocks/CU.
// Swapped QK^T; P in-register (cvt_pk + permlane32_swap); T13 defer-max.
__global__ __launch_bounds__(256, 3) void attn_kernel(
    const unsigned short* __restrict__ kbf, const unsigned short* __restrict__ qbf,
    const unsigned short* __restrict__ vt, float* __restrict__ partial)
{
    __shared__ __align__(16) char smem[40960];  // buf b at b*20480: q [32][128B], V [128][128B] at +4096

    const int tid = threadIdx.x;
    const int w = tid >> 6, lane = tid & 63;
    const int l31 = lane & 31, lh = lane >> 5;
    const int wi = w >> 1, wd = w & 1;
    const int wg = (blockIdx.x & 7) * 96 + (blockIdx.x >> 3);  // XCD-chunked, bijective
    const int h = wg >> 5, it = wg & 31;
    const int i0 = it * 64;

    const unsigned short* kh = kbf + (size_t)h * SLEN * HC;
    const unsigned short* qh = qbf + (size_t)h * SLEN * HC;
    const unsigned short* vh = vt + (size_t)h * ND * SLEN;

    // persistent k fragments (B-operand of QK): this wave's 32 i-rows
    short8 kf[4];
    {
        const unsigned short* kp = kh + (size_t)(i0 + wi * 32 + l31) * HC + lh * 8;
        #pragma unroll
        for (int ks = 0; ks < 4; ++ks) kf[ks] = *(const short8*)(kp + ks * 16);
    }

    f32x16 acc[4];
    #pragma unroll
    for (int nf = 0; nf < 4; ++nf)
        #pragma unroll
        for (int r = 0; r < 16; ++r) acc[nf][r] = 0.f;
    float m_run = -1e30f, l_run = 0.f;

    // stage j-tile jt into buffer at byte offset bufo.
    // 20 chunks of 1KB: 0..3 = q tile [32 rows][128B]; 4..19 = V tile [128 rows][128B]
    // V row = d>>1, col = (d&1)*64 + j*2; all rows XOR-swizzled by ((row&7)<<4).
    auto stage = [&](int bufo, int jt) {
        const int j0n = jt * 32;
        #pragma unroll
        for (int i = 0; i < 5; ++i) {
            const int c = i * 4 + w;
            const int lrow = (lane >> 3);
            const int cu = (((lane & 7) << 4) ^ (lrow << 4));   // unswizzled col byte
            if (c < 4) {   // q chunk c: rows 8c..8c+7
                const int row = c * 8 + lrow;                    // j local
                gload_lds16(qh + (size_t)(j0n + row) * HC + (cu >> 1),
                            smem + bufo + c * 1024);
            } else {       // V chunk: rows 8(c-4)..
                const int row = (c - 4) * 8 + lrow;
                const int d = row * 2 + (cu >> 6);
                const int j = (cu & 63) >> 1;
                gload_lds16(vh + (size_t)d * SLEN + j0n + j,
                            smem + bufo + 4096 + (c - 4) * 1024);
            }
        }
    };

    // softmax + pack one 32-j S block into two A-fragments (P in-register)
    auto softpack = [&](f32x16& S, uint4& p0, uint4& p1) {
        float tmax = S[0];
        #pragma unroll
        for (int r = 1; r < 16; ++r) tmax = fmaxf(tmax, S[r]);
        tmax = fmaxf(tmax, __shfl_xor(tmax, 32));
        if (!__all(tmax - m_run <= 8.0f)) {   // defer-max (T13)
            const float mnew = fmaxf(m_run, tmax);
            const float sc = __expf(m_run - mnew);
            l_run *= sc; m_run = mnew;
            #pragma unroll
            for (int r = 0; r < 16; ++r) {
                const float scv = __shfl(sc, (r & 3) + 8 * (r >> 2) + 4 * lh);
                #pragma unroll
                for (int nf = 0; nf < 4; ++nf) acc[nf][r] *= scv;
            }
        }
        float psum = 0.f;
        #pragma unroll
        for (int r = 0; r < 16; ++r) {
            S[r] = __expf(S[r] - m_run);
            psum += S[r];
        }
        psum += __shfl_xor(psum, 32);
        l_run += psum;
        uint2e r1 = __builtin_amdgcn_permlane32_swap(cvtpk(S[0], S[1]), cvtpk(S[4], S[5]), false, false);
        uint2e r2 = __builtin_amdgcn_permlane32_swap(cvtpk(S[2], S[3]), cvtpk(S[6], S[7]), false, false);
        uint2e r3 = __builtin_amdgcn_permlane32_swap(cvtpk(S[8], S[9]), cvtpk(S[12], S[13]), false, false);
        uint2e r4 = __builtin_amdgcn_permlane32_swap(cvtpk(S[10], S[11]), cvtpk(S[14], S[15]), false, false);
        p0 = make_uint4(r1[0], r2[0], r1[1], r2[1]);
        p1 = make_uint4(r3[0], r4[0], r3[1], r4[1]);
    };

    stage(0, 0);
    __syncthreads();

    for (int jt = 0; jt < NT; ++jt) {
        const int bo = (jt & 1) * 20480;
        if (jt + 1 < NT) stage(20480 - bo, jt + 1);
        const char* qb = smem + bo;
        const char* vb = smem + bo + 4096;

        // QK^T: A = q rows (j local = l31), B = kf  ->  S^T[j, i], lane col = i
        f32x16 S;
        #pragma unroll
        for (int r = 0; r < 16; ++r) S[r] = 0.f;
        const int qsw = (l31 & 7) << 4;
        __builtin_amdgcn_s_setprio(1);
        #pragma unroll
        for (int ks = 0; ks < 4; ++ks) {
            short8 a = *(const short8*)(qb + l31 * 128 + ((ks * 32 + lh * 16) ^ qsw));
            S = __builtin_amdgcn_mfma_f32_32x32x16_bf16(a, kf[ks], S, 0, 0, 0);
        }
        __builtin_amdgcn_s_setprio(0);

        uint4 p0, p1;
        softpack(S, p0, p1);

        // PV: A = P (regs), B = V (LDS packed [d>>1][(d&1)*64 + j*2])
        __builtin_amdgcn_s_setprio(1);
        #pragma unroll
        for (int ksl = 0; ksl < 2; ++ksl) {
            const short8 pa = *(const short8*)(ksl ? &p1 : &p0);
            #pragma unroll
            for (int nf = 0; nf < 4; ++nf) {
                const int d = wd * 128 + nf * 32 + l31;
                const int row = d >> 1;
                const int colb = (((d & 1) << 6) + ksl * 32 + lh * 16) ^ ((row & 7) << 4);
                short8 vfrag = *(const short8*)(vb + row * 128 + colb);
                acc[nf] = __builtin_amdgcn_mfma_f32_32x32x16_bf16(pa, vfrag, acc[nf], 0, 0, 0);
            }
        }
        __builtin_amdgcn_s_setprio(0);
        __syncthreads();
    }

    // epilogue: divide by l (broadcast via shfl), atomic head-group sum
    float* pb = partial + (size_t)(h / 3) * (SLEN * ND);
    const float invm = 1.0f / l_run;
    float lv[16];
    #pragma unroll
    for (int r = 0; r < 16; ++r)
        lv[r] = __shfl(invm, (r & 3) + 8 * (r >> 2) + 4 * lh);
    #pragma unroll
    for (int nf = 0; nf < 4; ++nf) {
        const int d = wd * 128 + nf * 32 + l31;
        #pragma unroll
        for (int r = 0; r < 16; ++r) {
            const int i = i0 + wi * 32 + (r & 3) + 8 * (r >> 2) + 4 * lh;
            atomicAdd(pb + (size_t)i * ND + d, acc[nf][r] * lv[r]);
        }
    }
}

// ---------------- K4: reduce 8 partials -> out ----------------
__global__ __launch_bounds__(256) void reduce_kernel(
    const float4* __restrict__ partial, float4* __restrict__ out)
{
    const size_t id = (size_t)blockIdx.x * 256 + threadIdx.x;
    float4 s = make_float4(0.f, 0.f, 0.f, 0.f);
    #pragma unroll
    for (int g = 0; g < 8; ++g) {
        float4 v = partial[g * (SLEN * ND / 4) + id];
        s.x += v.x; s.y += v.y; s.z += v.z; s.w += v.w;
    }
    out[id] = s;
}

extern "C" void kernel_launch(void* const* d_in, const int* in_sizes, int n_in,
                              void* d_out, int out_size, void* d_ws, size_t ws_size,
                              hipStream_t stream) {
    const float* nodes = (const float*)d_in[0];
    const float* pos   = (const float*)d_in[1];
    const float* aux   = (const float*)d_in[2];
    const float* Wn    = (const float*)d_in[3];
    const float* bn    = (const float*)d_in[4];
    const float* Wp    = (const float*)d_in[5];
    const float* bp    = (const float*)d_in[6];
    const float* Wa    = (const float*)d_in[7];
    const float* Wv    = (const float*)d_in[8];
    const float* bv    = (const float*)d_in[9];
    float* out = (float*)d_out;

    const size_t KQ   = (size_t)SLEN * NH * HC;   // 3,145,728 bf16 each
    const size_t VT   = (size_t)NH * ND * SLEN;   // 12,582,912 bf16
    const size_t WVBF = (size_t)6144 * ND;        // bf16
    const size_t WNBF = (size_t)1024 * ND;        // bf16
    const size_t NDBF = (size_t)SLEN * ND;        // bf16
    const size_t POSF = (size_t)SLEN * 8;         // f32
    const size_t KQT  = (size_t)SLEN * 1024;      // f32
    const size_t PART = (size_t)8 * SLEN * ND;    // f32
    const size_t need = (2 * KQ + VT + WVBF + WNBF + NDBF) * 2 + (POSF + KQT + PART) * 4;

    if (ws_size < need) return;

    unsigned short* kbf = (unsigned short*)d_ws;
    unsigned short* qbf = kbf + KQ;
    unsigned short* vt  = qbf + KQ;
    unsigned short* wv_bf = vt + VT;
    unsigned short* wn_bf = wv_bf + WVBF;
    unsigned short* nodes_bf = wn_bf + WNBF;
    float* pos_f   = (float*)(nodes_bf + NDBF);
    float* kqtmp   = pos_f + POSF;
    float* partial = kqtmp + KQT;

    zero_partial_kernel<<<PART / 1024, 256, 0, stream>>>((float4*)partial);
    f32_to_bf16_kernel<<<1536, 256, 0, stream>>>((const float4*)Wv, (uint2*)wv_bf);
    f32_to_bf16_kernel<<<256, 256, 0, stream>>>((const float4*)Wn, (uint2*)wn_bf);
    f32_to_bf16_kernel<<<512, 256, 0, stream>>>((const float4*)nodes, (uint2*)nodes_bf);
    posf_kernel<<<8, 256, 0, stream>>>(pos, pos_f);
    gemm_kernel<<<896, 256, 0, stream>>>(wv_bf, wn_bf, nodes_bf, bv, vt, kqtmp);
    kq_epi_kernel<<<8192, 256, 0, stream>>>(kqtmp, pos_f, aux, bn, bp, Wp, Wa, kbf, qbf);
    attn_kernel<<<768, 256, 0, stream>>>(kbf, qbf, vt, partial);
    reduce_kernel<<<512, 256, 0, stream>>>((const float4*)partial, (float4*)out);
}